// Round 8
// baseline (93.836 us; speedup 1.0000x reference)
//
#include <hip/hip_runtime.h>

// ---------------- fixed problem geometry (validated by out_size) -------------
#define NBATCH   8
#define TT       8
#define NPTS     6890
#define KCLS     7
#define CCH      128
#define BSAMP    64            // NBATCH*TT
#define NOUT     1722          // n = NPTS/4
#define DSUM     512
#define PCADIM   64
#define V3       23106         // 7702*3
#define EPSBN    1e-5f

#define NW       108           // mask words per sample (64 pts each)
#define PCH      128           // points per gather chunk (= 2 mask words)
#define CHB      2             // channel blocks (64 ch each)
#define CHN      64            // channels per ch-block
#define LDSQ     129           // padded point dim (channel-major LDS)
#define CPG      9             // chunks per gather block (pipelined)
#define NGRP     6             // 6 groups * 9 chunks = 54 chunks
#define K4B      91            // tpose blocks (first in K2 grid)
#define NSCAN    BSAMP         // scan/gv blocks (next in K2 grid)
#define NGATHER  (BSAMP * CHB * NGRP)   // 768; K2 grid total = 923 (all resident)

// output layout (flat f32)
#define OFF_GV     0
#define OFF_GF     (BSAMP * NOUT * 3)                 // 330624
#define OFF_COEFF  (OFF_GF + BSAMP * NOUT * CCH)      // 14437248
#define OFF_TPOSE  (OFF_COEFF + NBATCH * PCADIM)      // 14437760

// ------- kernel 1: {argmax mask (1728 blocks)} || {MLP (8 blocks)} -----------
__global__ __launch_bounds__(256) void k1_mask_mlp(
    const float* __restrict__ logits,            // [BSAMP, NPTS, KCLS]
    const int*   __restrict__ d_label,
    unsigned long long* __restrict__ ws_mask,    // [BSAMP, NW]
    const float* __restrict__ gsum,
    const float* __restrict__ W1, const float* __restrict__ b1,
    const float* __restrict__ g1, const float* __restrict__ be1,
    const float* __restrict__ rm1, const float* __restrict__ rv1,
    const float* __restrict__ W2, const float* __restrict__ b2,
    const float* __restrict__ g2, const float* __restrict__ be2,
    const float* __restrict__ rm2, const float* __restrict__ rv2,
    const float* __restrict__ W3, const float* __restrict__ b3,
    float* __restrict__ coeff_out, float* __restrict__ coeff_ws)
{
    const int tid = threadIdx.x;

    if (blockIdx.x < BSAMP * 27) {
        // ---------------- mask part ----------------
        const int b     = blockIdx.x / 27;
        const int chunk = blockIdx.x % 27;
        const int i     = chunk * 256 + tid;
        const int label = d_label[0];

        bool sel = false;
        if (i < NPTS) {
            const float* p = logits + ((size_t)b * NPTS + i) * KCLS;
            float best = p[0]; int bi = 0;
            #pragma unroll
            for (int k = 1; k < KCLS; ++k) {
                float v = p[k];
                if (v > best) { best = v; bi = k; }
            }
            sel = (bi == label);
        }
        const unsigned long long m = __ballot(sel);
        if ((tid & 63) == 0) {
            const int w = chunk * 4 + (tid >> 6);
            if (w < NW) ws_mask[b * NW + w] = m;
        }
    } else {
        // ---------------- MLP part (8 blocks) ----------------
        const int s    = blockIdx.x - BSAMP * 27;
        const int lane = tid & 63;
        const int wv   = tid >> 6;

        __shared__ float gs[DSUM];
        __shared__ float h1[128];
        __shared__ float h2[64];

        for (int d = tid; d < DSUM; d += 256) {
            const float* p = gsum + ((size_t)s * TT) * DSUM + d;
            float m = p[0];
            #pragma unroll
            for (int t = 1; t < TT; ++t) m = fmaxf(m, p[(size_t)t * DSUM]);
            gs[d] = m;
        }
        __syncthreads();

        for (int r = 0; r < 32; r += 2) {
            const int j0 = wv * 32 + r, j1 = j0 + 1;
            const float* w0 = W1 + (size_t)j0 * DSUM;
            const float* w1 = W1 + (size_t)j1 * DSUM;
            float pa = 0.f, pb = 0.f;
            #pragma unroll
            for (int d = lane; d < DSUM; d += 64) {
                const float gd = gs[d];
                pa = fmaf(w0[d], gd, pa);
                pb = fmaf(w1[d], gd, pb);
            }
            #pragma unroll
            for (int off = 32; off; off >>= 1) {
                pa += __shfl_xor(pa, off);
                pb += __shfl_xor(pb, off);
            }
            if (lane == 0) {
                pa += b1[j0];
                pa = (pa - rm1[j0]) * rsqrtf(rv1[j0] + EPSBN) * g1[j0] + be1[j0];
                h1[j0] = fmaxf(pa, 0.f);
                pb += b1[j1];
                pb = (pb - rm1[j1]) * rsqrtf(rv1[j1] + EPSBN) * g1[j1] + be1[j1];
                h1[j1] = fmaxf(pb, 0.f);
            }
        }
        __syncthreads();

        for (int r = 0; r < 16; ++r) {
            const int jj = wv * 16 + r;
            const float* w = W2 + (size_t)jj * 128;
            float p = w[lane] * h1[lane] + w[lane + 64] * h1[lane + 64];
            #pragma unroll
            for (int off = 32; off; off >>= 1) p += __shfl_xor(p, off);
            if (lane == 0) {
                p += b2[jj];
                p = (p - rm2[jj]) * rsqrtf(rv2[jj] + EPSBN) * g2[jj] + be2[jj];
                h2[jj] = fmaxf(p, 0.f);
            }
        }
        __syncthreads();

        for (int r = 0; r < 16; ++r) {
            const int jj = wv * 16 + r;
            float p = W3[(size_t)jj * 64 + lane] * h2[lane];
            #pragma unroll
            for (int off = 32; off; off >>= 1) p += __shfl_xor(p, off);
            if (lane == 0) {
                p += b3[jj];
                coeff_out[s * PCADIM + jj] = p;
                coeff_ws[s * PCADIM + jj]  = p;
            }
        }
    }
}

// ------- kernel 2: {tpose (91)} || {scan/gv (64)} || {gather (768)} ----------
__global__ __launch_bounds__(256, 4) void k2_all(
    const float* __restrict__ feature,           // [BSAMP, CCH, NPTS]
    const unsigned long long* __restrict__ ws_mask,
    const float* __restrict__ x,                 // [BSAMP, NPTS, 3]
    float* __restrict__ gv,                      // [BSAMP, NOUT, 3]
    float* __restrict__ gf,                      // [BSAMP, NOUT, CCH]
    const float* __restrict__ coeff_ws,
    const float* __restrict__ comp,
    const float* __restrict__ mean_,
    const float* __restrict__ scale_,
    float* __restrict__ tpose)
{
    __shared__ float lds[CHN * LDSQ];            // 33 KB (also reused by tpose)
    __shared__ unsigned long long smask[NW];
    __shared__ int  swc[NW];                     // popcount -> exclusive prefix
    __shared__ int  spos[PCH];
    __shared__ int  sel_list[PCH];
    __shared__ int  s_ns[2];
    __shared__ int  s_cnt;

    const int tid = threadIdx.x;

    if (blockIdx.x < K4B) {
        // ---------------- tpose part ----------------
        float* sc = lds;
        for (int o = tid; o < NBATCH * PCADIM; o += 256) sc[o] = coeff_ws[o];
        __syncthreads();

        const int v = blockIdx.x * 256 + tid;
        if (v >= V3) return;

        float acc[NBATCH];
        #pragma unroll
        for (int s = 0; s < NBATCH; ++s) acc[s] = 0.f;
        for (int k = 0; k < PCADIM; ++k) {
            const float pv = comp[(size_t)k * V3 + v];
            #pragma unroll
            for (int s = 0; s < NBATCH; ++s)
                acc[s] = fmaf(sc[s * PCADIM + k], pv, acc[s]);
        }
        const float mn = mean_[v], scl = scale_[v];
        #pragma unroll
        for (int s = 0; s < NBATCH; ++s)
            tpose[(size_t)s * V3 + v] = (acc[s] + mn) * scl;
        return;
    }

    if (blockIdx.x < K4B + NSCAN) {
        // ---------------- scan/gv part ----------------
        const int b = blockIdx.x - K4B;

        if (tid < NW) smask[tid] = ws_mask[b * NW + tid];
        __syncthreads();
        if (tid < NW) swc[tid] = __popcll(smask[tid]);
        __syncthreads();
        if (tid == 0) {
            int run = 0;
            for (int w = 0; w < NW; ++w) { int t = swc[w]; swc[w] = run; run += t; }
            s_cnt = run < NOUT ? run : NOUT;
        }
        __syncthreads();

        const float* xb = x + (size_t)b * NPTS * 3;
        for (int i = tid; i < NPTS; i += 256) {
            const int w = i >> 6, lb6 = i & 63;
            const unsigned long long m = smask[w];
            if ((m >> lb6) & 1ull) {
                const int pos = swc[w] + __popcll(m & ((1ull << lb6) - 1ull));
                if (pos < NOUT) {
                    const size_t go = ((size_t)b * NOUT + pos) * 3;
                    gv[go + 0] = xb[(size_t)i * 3 + 0];
                    gv[go + 1] = xb[(size_t)i * 3 + 1];
                    gv[go + 2] = xb[(size_t)i * 3 + 2];
                }
            }
        }
        for (int j = s_cnt + tid; j < NOUT; j += 256) {
            float* gp = gv + ((size_t)b * NOUT + j) * 3;
            gp[0] = 0.f; gp[1] = 0.f; gp[2] = 0.f;
        }
        return;
    }

    // ---------------- gather part ----------------
    const int gb  = blockIdx.x - (K4B + NSCAN);
    const int b   = gb / (CHB * NGRP);
    const int rem = gb % (CHB * NGRP);
    const int cb  = rem / NGRP;
    const int g   = rem % NGRP;

    const int lane = tid & 63;                   // float2 slot -> points 2l, 2l+1
    const int cg   = tid >> 6;                   // 0..3 -> 16 channels each
    const int p0   = lane * 2;
    const float* fbase = feature + ((size_t)b * CCH + cb * CHN) * NPTS;

    float2 rc[16], rn[16];

    // 1) prologue: issue loads for chunk g*CPG (in flight during prefix setup)
    {
        const int i0 = g * (CPG * PCH);
        const int il = min(PCH, NPTS - i0);
        const float* fb = fbase + i0 + p0;
        if (p0 < il) {
            #pragma unroll
            for (int it = 0; it < 16; ++it)
                rc[it] = *(const float2*)(fb + (size_t)(cg * 16 + it) * NPTS);
        } else {
            #pragma unroll
            for (int it = 0; it < 16; ++it) rc[it] = make_float2(0.f, 0.f);
        }
    }

    // 2) local mask + prefix (hidden under the in-flight loads)
    if (tid < NW) smask[tid] = ws_mask[b * NW + tid];
    __syncthreads();
    if (tid < NW) swc[tid] = __popcll(smask[tid]);
    __syncthreads();
    if (tid == 0) {
        int run = 0;
        for (int w = 0; w < NW; ++w) { int t = swc[w]; swc[w] = run; run += t; }
        s_cnt = run < NOUT ? run : NOUT;
    }
    __syncthreads();

    // 3) gf tail-zero share (independent stores; also hide under load wait)
    {
        const int cnt  = s_cnt;
        const int tail = NOUT - cnt;
        if (tail > 0) {
            const int nshares = CHB * NGRP;                    // 12
            const int share = (tail + nshares - 1) / nshares;
            const int idx   = cb * NGRP + g;
            const int r0    = cnt + idx * share;
            const int r1    = min(r0 + share, NOUT);
            const int nrows = r1 - r0;
            if (nrows > 0) {
                float4* base4 = (float4*)(gf + ((size_t)b * NOUT + r0) * CCH);
                const int total = nrows * 32;
                for (int f = tid; f < total; f += 256)
                    base4[f] = make_float4(0.f, 0.f, 0.f, 0.f);
            }
        }
    }

    // 4) pipelined chunk loop
    #pragma unroll 1
    for (int c = 0; c < CPG; ++c) {
        const int chunk = g * CPG + c;

        if (c + 1 < CPG) {
            const int i1 = (chunk + 1) * PCH;
            const int il = min(PCH, NPTS - i1);
            const float* fb = fbase + i1 + p0;
            if (p0 < il) {
                #pragma unroll
                for (int it = 0; it < 16; ++it)
                    rn[it] = *(const float2*)(fb + (size_t)(cg * 16 + it) * NPTS);
            } else {
                #pragma unroll
                for (int it = 0; it < 16; ++it) rn[it] = make_float2(0.f, 0.f);
            }
        }

        __syncthreads();                          // LDS free (prev phase B done)

        // LDS write, channel-major (2-way banks, free)
        #pragma unroll
        for (int it = 0; it < 16; ++it) {
            const int cch = cg * 16 + it;
            lds[cch * LDSQ + p0]     = rc[it].x;
            lds[cch * LDSQ + p0 + 1] = rc[it].y;
        }

        // selection for the chunk's two mask words (waves 0 and 1, LDS-based)
        if (tid < 128) {
            const int w    = tid >> 6;
            const int word = 2 * chunk + w;
            const unsigned long long m = smask[word];
            const int base = swc[word];
            const int sel  = (int)((m >> lane) & 1ull);
            const int pos  = base + __popcll(m & ((1ull << lane) - 1ull));
            const int sp   = (sel && pos < NOUT) ? pos : -1;
            spos[tid] = sp;
            const unsigned long long mm = __ballot(sp >= 0);
            const int before = __popcll(mm & ((1ull << lane) - 1ull));
            if (sp >= 0) sel_list[w * 64 + before] = tid;
            if (lane == 0) s_ns[w] = __popcll(mm);
        }
        __syncthreads();

        // phase B: 256B half-row writes, 4 rows in parallel (1 per wave)
        const int rw = tid >> 6;
        #pragma unroll 1
        for (int w = 0; w < 2; ++w) {
            const int ns = s_ns[w];
            for (int s = rw; s < ns; s += 4) {
                const int p   = sel_list[w * 64 + s];
                const int pos = spos[p];
                gf[((size_t)b * NOUT + pos) * CCH + cb * CHN + lane] =
                    lds[lane * LDSQ + p];
            }
        }

        if (c + 1 < CPG) {
            #pragma unroll
            for (int it = 0; it < 16; ++it) rc[it] = rn[it];
        }
    }
}

// ---------------- launcher ---------------------------------------------------
extern "C" void kernel_launch(void* const* d_in, const int* in_sizes, int n_in,
                              void* d_out, int out_size, void* d_ws, size_t ws_size,
                              hipStream_t stream) {
    const float* x      = (const float*)d_in[0];
    const float* logits = (const float*)d_in[1];
    const float* feat   = (const float*)d_in[2];
    const float* gsum   = (const float*)d_in[3];
    const float* W1  = (const float*)d_in[4];
    const float* b1  = (const float*)d_in[5];
    const float* g1  = (const float*)d_in[6];
    const float* be1 = (const float*)d_in[7];
    const float* rm1 = (const float*)d_in[8];
    const float* rv1 = (const float*)d_in[9];
    const float* W2  = (const float*)d_in[10];
    const float* b2  = (const float*)d_in[11];
    const float* g2  = (const float*)d_in[12];
    const float* be2 = (const float*)d_in[13];
    const float* rm2 = (const float*)d_in[14];
    const float* rv2 = (const float*)d_in[15];
    const float* W3  = (const float*)d_in[16];
    const float* b3  = (const float*)d_in[17];
    const float* comp  = (const float*)d_in[18];
    const float* mean_ = (const float*)d_in[19];
    const float* scale_= (const float*)d_in[20];
    const int* d_label = (const int*)d_in[21];

    float* out   = (float*)d_out;
    float* gv    = out + OFF_GV;
    float* gf    = out + OFF_GF;
    float* coeff = out + OFF_COEFF;
    float* tpose = out + OFF_TPOSE;

    unsigned long long* ws_mask = (unsigned long long*)d_ws;      // 64*108 u64
    float* coeff_ws = (float*)(ws_mask + BSAMP * NW);             // 512 f32

    k1_mask_mlp<<<BSAMP * 27 + NBATCH, 256, 0, stream>>>(
        logits, d_label, ws_mask, gsum, W1, b1, g1, be1, rm1, rv1,
        W2, b2, g2, be2, rm2, rv2, W3, b3, coeff, coeff_ws);

    k2_all<<<K4B + NSCAN + NGATHER, 256, 0, stream>>>(
        feat, ws_mask, x, gv, gf, coeff_ws, comp, mean_, scale_, tpose);
}

// Round 9
// 90.038 us; speedup vs baseline: 1.0422x; 1.0422x over previous
//
#include <hip/hip_runtime.h>

// ---------------- fixed problem geometry (validated by out_size) -------------
#define NBATCH   8
#define TT       8
#define NPTS     6890
#define KCLS     7
#define CCH      128
#define BSAMP    64            // NBATCH*TT
#define NOUT     1722          // n = NPTS/4
#define DSUM     512
#define PCADIM   64
#define V3       23106         // 7702*3
#define EPSBN    1e-5f

#define NW       108           // mask words per sample (64 pts each)
#define PCH      256           // points per gather chunk (= 4 mask words)
#define CHB      4             // channel blocks (32 ch each)
#define CHN      32            // channels per ch-block
#define LDSR     260           // padded point dim (row-major [ch][pt] LDS, 16B-aligned rows)
#define CPG      9             // chunks per gather block (pipelined)
#define NGRP     3             // 3 groups * 9 chunks = 27 chunks (27*256=6912>=6890)
#define K4B      91            // tpose blocks (first in K2 grid)
#define NSCAN    BSAMP         // scan/gv blocks (next in K2 grid)
#define NGATHER  (BSAMP * CHB * NGRP)   // 768; K2 grid total = 923 (all resident)

// output layout (flat f32)
#define OFF_GV     0
#define OFF_GF     (BSAMP * NOUT * 3)                 // 330624
#define OFF_COEFF  (OFF_GF + BSAMP * NOUT * CCH)      // 14437248
#define OFF_TPOSE  (OFF_COEFF + NBATCH * PCADIM)      // 14437760

// ------- kernel 1: {argmax mask (1728 blocks)} || {MLP (8 blocks)} -----------
__global__ __launch_bounds__(256) void k1_mask_mlp(
    const float* __restrict__ logits,            // [BSAMP, NPTS, KCLS]
    const int*   __restrict__ d_label,
    unsigned long long* __restrict__ ws_mask,    // [BSAMP, NW]
    const float* __restrict__ gsum,
    const float* __restrict__ W1, const float* __restrict__ b1,
    const float* __restrict__ g1, const float* __restrict__ be1,
    const float* __restrict__ rm1, const float* __restrict__ rv1,
    const float* __restrict__ W2, const float* __restrict__ b2,
    const float* __restrict__ g2, const float* __restrict__ be2,
    const float* __restrict__ rm2, const float* __restrict__ rv2,
    const float* __restrict__ W3, const float* __restrict__ b3,
    float* __restrict__ coeff_out, float* __restrict__ coeff_ws)
{
    const int tid = threadIdx.x;

    if (blockIdx.x < BSAMP * 27) {
        // ---------------- mask part ----------------
        const int b     = blockIdx.x / 27;
        const int chunk = blockIdx.x % 27;
        const int i     = chunk * 256 + tid;
        const int label = d_label[0];

        bool sel = false;
        if (i < NPTS) {
            const float* p = logits + ((size_t)b * NPTS + i) * KCLS;
            float best = p[0]; int bi = 0;
            #pragma unroll
            for (int k = 1; k < KCLS; ++k) {
                float v = p[k];
                if (v > best) { best = v; bi = k; }
            }
            sel = (bi == label);
        }
        const unsigned long long m = __ballot(sel);
        if ((tid & 63) == 0) {
            const int w = chunk * 4 + (tid >> 6);
            if (w < NW) ws_mask[b * NW + w] = m;
        }
    } else {
        // ---------------- MLP part (8 blocks) ----------------
        const int s    = blockIdx.x - BSAMP * 27;
        const int lane = tid & 63;
        const int wv   = tid >> 6;

        __shared__ float gs[DSUM];
        __shared__ float h1[128];
        __shared__ float h2[64];

        for (int d = tid; d < DSUM; d += 256) {
            const float* p = gsum + ((size_t)s * TT) * DSUM + d;
            float m = p[0];
            #pragma unroll
            for (int t = 1; t < TT; ++t) m = fmaxf(m, p[(size_t)t * DSUM]);
            gs[d] = m;
        }
        __syncthreads();

        for (int r = 0; r < 32; r += 2) {
            const int j0 = wv * 32 + r, j1 = j0 + 1;
            const float* w0 = W1 + (size_t)j0 * DSUM;
            const float* w1 = W1 + (size_t)j1 * DSUM;
            float pa = 0.f, pb = 0.f;
            #pragma unroll
            for (int d = lane; d < DSUM; d += 64) {
                const float gd = gs[d];
                pa = fmaf(w0[d], gd, pa);
                pb = fmaf(w1[d], gd, pb);
            }
            #pragma unroll
            for (int off = 32; off; off >>= 1) {
                pa += __shfl_xor(pa, off);
                pb += __shfl_xor(pb, off);
            }
            if (lane == 0) {
                pa += b1[j0];
                pa = (pa - rm1[j0]) * rsqrtf(rv1[j0] + EPSBN) * g1[j0] + be1[j0];
                h1[j0] = fmaxf(pa, 0.f);
                pb += b1[j1];
                pb = (pb - rm1[j1]) * rsqrtf(rv1[j1] + EPSBN) * g1[j1] + be1[j1];
                h1[j1] = fmaxf(pb, 0.f);
            }
        }
        __syncthreads();

        for (int r = 0; r < 16; ++r) {
            const int jj = wv * 16 + r;
            const float* w = W2 + (size_t)jj * 128;
            float p = w[lane] * h1[lane] + w[lane + 64] * h1[lane + 64];
            #pragma unroll
            for (int off = 32; off; off >>= 1) p += __shfl_xor(p, off);
            if (lane == 0) {
                p += b2[jj];
                p = (p - rm2[jj]) * rsqrtf(rv2[jj] + EPSBN) * g2[jj] + be2[jj];
                h2[jj] = fmaxf(p, 0.f);
            }
        }
        __syncthreads();

        for (int r = 0; r < 16; ++r) {
            const int jj = wv * 16 + r;
            float p = W3[(size_t)jj * 64 + lane] * h2[lane];
            #pragma unroll
            for (int off = 32; off; off >>= 1) p += __shfl_xor(p, off);
            if (lane == 0) {
                p += b3[jj];
                coeff_out[s * PCADIM + jj] = p;
                coeff_ws[s * PCADIM + jj]  = p;
            }
        }
    }
}

// ------- kernel 2: {tpose (91)} || {scan/gv (64)} || {gather (768)} ----------
// Gather block = (b, cb of 32 channels, g of 9 chunks of 256 pts).
// Global read: float4/lane -> 1KB contiguous burst per wave-instruction.
// LDS [32ch][260pt]: write = full-row b128 streaming (conflict-free);
// read = per-selected-point column (banked, but only ~1/7 of volume).
__global__ __launch_bounds__(256, 4) void k2_all(
    const float* __restrict__ feature,           // [BSAMP, CCH, NPTS]
    const unsigned long long* __restrict__ ws_mask,
    const float* __restrict__ x,                 // [BSAMP, NPTS, 3]
    float* __restrict__ gv,                      // [BSAMP, NOUT, 3]
    float* __restrict__ gf,                      // [BSAMP, NOUT, CCH]
    const float* __restrict__ coeff_ws,
    const float* __restrict__ comp,
    const float* __restrict__ mean_,
    const float* __restrict__ scale_,
    float* __restrict__ tpose)
{
    __shared__ float lds[CHN * LDSR];            // 33280 B
    __shared__ unsigned long long smask[NW];
    __shared__ int  swc[NW];                     // popcount -> exclusive prefix
    __shared__ int  spos[PCH];                   // local pt -> output row (or -1)
    __shared__ int  sel_list[PCH];               // per-word compacted local pts
    __shared__ int  s_ns[4];
    __shared__ int  s_cnt;

    const int tid = threadIdx.x;

    if (blockIdx.x < K4B) {
        // ---------------- tpose part ----------------
        float* sc = lds;
        for (int o = tid; o < NBATCH * PCADIM; o += 256) sc[o] = coeff_ws[o];
        __syncthreads();

        const int v = blockIdx.x * 256 + tid;
        if (v >= V3) return;

        float acc[NBATCH];
        #pragma unroll
        for (int s = 0; s < NBATCH; ++s) acc[s] = 0.f;
        for (int k = 0; k < PCADIM; ++k) {
            const float pv = comp[(size_t)k * V3 + v];
            #pragma unroll
            for (int s = 0; s < NBATCH; ++s)
                acc[s] = fmaf(sc[s * PCADIM + k], pv, acc[s]);
        }
        const float mn = mean_[v], scl = scale_[v];
        #pragma unroll
        for (int s = 0; s < NBATCH; ++s)
            tpose[(size_t)s * V3 + v] = (acc[s] + mn) * scl;
        return;
    }

    if (blockIdx.x < K4B + NSCAN) {
        // ---------------- scan/gv part ----------------
        const int b = blockIdx.x - K4B;

        if (tid < NW) smask[tid] = ws_mask[b * NW + tid];
        __syncthreads();
        if (tid < NW) swc[tid] = __popcll(smask[tid]);
        __syncthreads();
        if (tid == 0) {
            int run = 0;
            for (int w = 0; w < NW; ++w) { int t = swc[w]; swc[w] = run; run += t; }
            s_cnt = run < NOUT ? run : NOUT;
        }
        __syncthreads();

        const float* xb = x + (size_t)b * NPTS * 3;
        for (int i = tid; i < NPTS; i += 256) {
            const int w = i >> 6, lb6 = i & 63;
            const unsigned long long m = smask[w];
            if ((m >> lb6) & 1ull) {
                const int pos = swc[w] + __popcll(m & ((1ull << lb6) - 1ull));
                if (pos < NOUT) {
                    const size_t go = ((size_t)b * NOUT + pos) * 3;
                    gv[go + 0] = xb[(size_t)i * 3 + 0];
                    gv[go + 1] = xb[(size_t)i * 3 + 1];
                    gv[go + 2] = xb[(size_t)i * 3 + 2];
                }
            }
        }
        for (int j = s_cnt + tid; j < NOUT; j += 256) {
            float* gp = gv + ((size_t)b * NOUT + j) * 3;
            gp[0] = 0.f; gp[1] = 0.f; gp[2] = 0.f;
        }
        return;
    }

    // ---------------- gather part ----------------
    const int gb  = blockIdx.x - (K4B + NSCAN);
    const int b   = gb / (CHB * NGRP);
    const int rem = gb % (CHB * NGRP);
    const int cb  = rem / NGRP;                  // 0..3
    const int g   = rem % NGRP;                  // 0..2

    const int lane = tid & 63;
    const int wv   = tid >> 6;                   // 0..3 -> rows wv*8..wv*8+7
    const int p4   = lane * 4;
    const float* fbase = feature + ((size_t)b * CCH + cb * CHN) * NPTS;

    float4 rc[8], rn[8];

    // 1) prologue: issue float4 loads for chunk g*CPG (stay in flight across barriers)
    {
        const int i0 = (g * CPG) * PCH;
        const int il = min(PCH, NPTS - i0);
        const float* fb = fbase + i0 + p4;
        if (p4 + 4 <= il) {
            #pragma unroll
            for (int it = 0; it < 8; ++it)
                rc[it] = *(const float4*)(fb + (size_t)(wv * 8 + it) * NPTS);
        } else if (p4 < il) {                    // il%4==2 tail (2 floats)
            #pragma unroll
            for (int it = 0; it < 8; ++it) {
                float2 v = *(const float2*)(fb + (size_t)(wv * 8 + it) * NPTS);
                rc[it] = make_float4(v.x, v.y, 0.f, 0.f);
            }
        } else {
            #pragma unroll
            for (int it = 0; it < 8; ++it) rc[it] = make_float4(0.f, 0.f, 0.f, 0.f);
        }
    }

    // 2) local mask + prefix (hidden under the in-flight loads)
    if (tid < NW) smask[tid] = ws_mask[b * NW + tid];
    __syncthreads();
    if (tid < NW) swc[tid] = __popcll(smask[tid]);
    __syncthreads();
    if (tid == 0) {
        int run = 0;
        for (int w = 0; w < NW; ++w) { int t = swc[w]; swc[w] = run; run += t; }
        s_cnt = run < NOUT ? run : NOUT;
    }
    __syncthreads();

    // 3) gf tail-zero share (independent stores; hide under load wait)
    {
        const int cnt  = s_cnt;
        const int tail = NOUT - cnt;
        if (tail > 0) {
            const int nshares = CHB * NGRP;                    // 12
            const int share = (tail + nshares - 1) / nshares;
            const int idx   = cb * NGRP + g;
            const int r0    = cnt + idx * share;
            const int r1    = min(r0 + share, NOUT);
            const int nrows = r1 - r0;
            if (nrows > 0) {
                float4* base4 = (float4*)(gf + ((size_t)b * NOUT + r0) * CCH);
                const int total = nrows * 32;
                for (int f = tid; f < total; f += 256)
                    base4[f] = make_float4(0.f, 0.f, 0.f, 0.f);
            }
        }
    }

    // 4) pipelined chunk loop
    #pragma unroll 1
    for (int c = 0; c < CPG; ++c) {
        const int chunk = g * CPG + c;

        if (c + 1 < CPG) {
            const int i1 = (chunk + 1) * PCH;
            const int il = min(PCH, NPTS - i1);
            const float* fb = fbase + i1 + p4;
            if (p4 + 4 <= il) {
                #pragma unroll
                for (int it = 0; it < 8; ++it)
                    rn[it] = *(const float4*)(fb + (size_t)(wv * 8 + it) * NPTS);
            } else if (p4 < il) {
                #pragma unroll
                for (int it = 0; it < 8; ++it) {
                    float2 v = *(const float2*)(fb + (size_t)(wv * 8 + it) * NPTS);
                    rn[it] = make_float4(v.x, v.y, 0.f, 0.f);
                }
            } else {
                #pragma unroll
                for (int it = 0; it < 8; ++it) rn[it] = make_float4(0.f, 0.f, 0.f, 0.f);
            }
        }

        __syncthreads();                          // LDS free (prev phase B done)

        // LDS write: full-row b128 streaming, conflict-free
        #pragma unroll
        for (int it = 0; it < 8; ++it) {
            const int r = wv * 8 + it;
            *(float4*)(&lds[r * LDSR + p4]) = rc[it];
        }

        // selection: wave wv handles mask word 4*chunk+wv (64 pts each)
        {
            const int word = 4 * chunk + wv;
            const unsigned long long m = smask[word];
            const int base = swc[word];
            const int sel  = (int)((m >> lane) & 1ull);
            const int pos  = base + __popcll(m & ((1ull << lane) - 1ull));
            const int sp   = (sel && pos < NOUT) ? pos : -1;
            const int plocal = wv * 64 + lane;    // point index within chunk
            spos[plocal] = sp;
            const unsigned long long mm = __ballot(sp >= 0);
            const int before = __popcll(mm & ((1ull << lane) - 1ull));
            if (sp >= 0) sel_list[wv * 64 + before] = plocal;
            if (lane == 0) s_ns[wv] = __popcll(mm);
        }
        __syncthreads();

        // phase B: per-point 128B row writes; wave wv drains its word's list,
        // 2 points per wave-op (lanes 0-31 / 32-63)
        {
            const int ns   = s_ns[wv];
            const int half = lane >> 5;
            const int ch   = lane & 31;
            for (int s = half; s < ns; s += 2) {
                const int p   = sel_list[wv * 64 + s];
                const int pos = spos[p];
                gf[((size_t)b * NOUT + pos) * CCH + cb * CHN + ch] =
                    lds[ch * LDSR + p];
            }
        }

        if (c + 1 < CPG) {
            #pragma unroll
            for (int it = 0; it < 8; ++it) rc[it] = rn[it];
        }
    }
}

// ---------------- launcher ---------------------------------------------------
extern "C" void kernel_launch(void* const* d_in, const int* in_sizes, int n_in,
                              void* d_out, int out_size, void* d_ws, size_t ws_size,
                              hipStream_t stream) {
    const float* x      = (const float*)d_in[0];
    const float* logits = (const float*)d_in[1];
    const float* feat   = (const float*)d_in[2];
    const float* gsum   = (const float*)d_in[3];
    const float* W1  = (const float*)d_in[4];
    const float* b1  = (const float*)d_in[5];
    const float* g1  = (const float*)d_in[6];
    const float* be1 = (const float*)d_in[7];
    const float* rm1 = (const float*)d_in[8];
    const float* rv1 = (const float*)d_in[9];
    const float* W2  = (const float*)d_in[10];
    const float* b2  = (const float*)d_in[11];
    const float* g2  = (const float*)d_in[12];
    const float* be2 = (const float*)d_in[13];
    const float* rm2 = (const float*)d_in[14];
    const float* rv2 = (const float*)d_in[15];
    const float* W3  = (const float*)d_in[16];
    const float* b3  = (const float*)d_in[17];
    const float* comp  = (const float*)d_in[18];
    const float* mean_ = (const float*)d_in[19];
    const float* scale_= (const float*)d_in[20];
    const int* d_label = (const int*)d_in[21];

    float* out   = (float*)d_out;
    float* gv    = out + OFF_GV;
    float* gf    = out + OFF_GF;
    float* coeff = out + OFF_COEFF;
    float* tpose = out + OFF_TPOSE;

    unsigned long long* ws_mask = (unsigned long long*)d_ws;      // 64*108 u64
    float* coeff_ws = (float*)(ws_mask + BSAMP * NW);             // 512 f32

    k1_mask_mlp<<<BSAMP * 27 + NBATCH, 256, 0, stream>>>(
        logits, d_label, ws_mask, gsum, W1, b1, g1, be1, rm1, rv1,
        W2, b2, g2, be2, rm2, rv2, W3, b3, coeff, coeff_ws);

    k2_all<<<K4B + NSCAN + NGATHER, 256, 0, stream>>>(
        feat, ws_mask, x, gv, gf, coeff_ws, comp, mean_, scale_, tpose);
}